// Round 12
// baseline (21.049 us; speedup 1.0000x reference)
//
#include <hip/hip_runtime.h>
#include <math.h>

#define NA 512
#define NQC 8

#define NCf ((float)(90.4756 / 6.28318530717958647692))
#define A_ERF 0.70710678118654752f      // 1/sqrt(2)
#define G_COEF 0.79788456080286536f     // sqrt(2/pi)

// ---------------- main kernel ----------------
// grid = 512 blocks (receiver j), block = 512 threads = 8 waves.
// R10 structure (wave-level coefficient sharing via __shfl) + per-k LDS slab
// staging: records for iteration k (iq = k*512 + tid) are CONTIGUOUS in the
// raw quad/u arrays, so the block copies the whole slab with flat coalesced
// loads (lds[tid+m*512] = src[tid+m*512]) into a double buffer, then each
// thread reads its record at stride 9 (odd -> 2-way bank alias, free).
// Replaces ~160 cacheline-touches/wave-iter of strided loads with ~14.
__global__ __launch_bounds__(512)
void main_kernel(const float* __restrict__ qarr,
                 const float* __restrict__ rarr,
                 const float* __restrict__ uarr,
                 const float* __restrict__ quadarr,
                 const float* __restrict__ kaparr,
                 const float* __restrict__ alparr,
                 float* __restrict__ out,
                 float* __restrict__ potpart) {
    const int j    = blockIdx.x;
    const int tid  = threadIdx.x;
    const int qch  = tid & 7;
    const int lane = tid & 63;
    const int wv   = tid >> 6;     // 8 waves

    __shared__ float sQ[2][NA * 9];   // 36 KB: quad slab double buffer
    __shared__ float sU[2][NA * 3];   // 12 KB: u slab double buffer

    const float rjx = rarr[j*3+0], rjy = rarr[j*3+1], rjz = rarr[j*3+2];

    const int jq = j * NQC + qch;
    const float* Qj = quadarr + (size_t)jq * 9;
    const float jxx = Qj[0], jyy = Qj[4], jzz = Qj[8];
    const float jxy = 0.5f*(Qj[1]+Qj[3]);
    const float jxz = 0.5f*(Qj[2]+Qj[6]);
    const float jyz = 0.5f*(Qj[5]+Qj[7]);
    const float jtq = jxx + jyy + jzz;

    // ---- coefficient pass: one pair per lane (covers all 8 k-iters) ----
    float mc0, mc1, mc2, mc3, mc4, mdx, mdy, mdz;
    {
        const int myi = ((lane >> 3) << 6) + (wv << 3) + (lane & 7);
        mdx = rjx - rarr[myi*3+0];
        mdy = rjy - rarr[myi*3+1];
        mdz = rjz - rarr[myi*3+2];
        float r2 = mdx*mdx + mdy*mdy + mdz*mdz;
        const bool diag = (myi == j);
        if (diag) r2 = 1.0f;
        const float ir  = rsqrtf(r2);
        const float rr  = r2 * ir;
        // branch-free erf(rr/sqrt(2)) — A&S 7.1.26, exp shared with G
        const float x   = A_ERF * rr;
        const float E2  = __expf(-0.5f * r2);  // == exp(-x*x)
        const float G   = G_COEF * E2;
        const float t   = __builtin_amdgcn_rcpf(fmaf(0.3275911f, x, 1.0f));
        const float pol = t*(0.254829592f + t*(-0.284496736f + t*(1.421413741f
                         + t*(-1.453152027f + t*1.061405429f))));
        const float E   = fmaf(-pol, E2, 1.0f);
        const float ir2 = ir * ir;
        const float ir4 = ir2 * ir2;
        const float g   = E * ir;
        const float GmG = G - g;
        const float nco = diag ? 0.0f : NCf;
        mc0 = nco * g;
        mc1 = nco * ir2 * GmG;
        mc2 = nco * ir2 * (-3.0f*ir2*GmG - G);
        mc3 = nco * ir2 * (15.0f*ir4*GmG + 5.0f*G*ir2 + G);
        mc4 = nco * ir2 * (-105.0f*ir4*ir2*GmG - 35.0f*G*ir4 - 7.0f*G*ir2 - G);
    }

    // ---- prologue: stage slab 0 (flat coalesced copies) ----
    {
        const float* srcQ = quadarr;           // slab 0: floats [0, 4608)
        #pragma unroll
        for (int m = 0; m < 9; ++m) sQ[0][tid + m*512] = srcQ[tid + m*512];
        const float* srcU = uarr;              // slab 0: floats [0, 1536)
        #pragma unroll
        for (int m = 0; m < 3; ++m) sU[0][tid + m*512] = srcU[tid + m*512];
    }
    __syncthreads();

    float e0 = 0.f, eph = 0.f;
    float Fx = 0.f, Fy = 0.f, Fz = 0.f;
    float Hx = 0.f, Hy = 0.f, Hz = 0.f;
    float pQQ = 0.f;

    #pragma unroll 2
    for (int k = 0; k < 8; ++k) {
        const int cur = k & 1, nxt = cur ^ 1;

        // stage slab k+1 into the other buffer (overlaps compute below)
        if (k < 7) {
            const float* srcQ = quadarr + (size_t)(k+1) * (NA * 9);
            #pragma unroll
            for (int m = 0; m < 9; ++m) sQ[nxt][tid + m*512] = srcQ[tid + m*512];
            const float* srcU = uarr + (size_t)(k+1) * (NA * 3);
            #pragma unroll
            for (int m = 0; m < 3; ++m) sU[nxt][tid + m*512] = srcU[tid + m*512];
        }

        const int iq  = k * 512 + tid;            // record this thread consumes
        const int src = (k << 3) + (lane >> 3);   // lane holding this pair's coeffs

        const float c0 = __shfl(mc0, src, 64);
        const float c1 = __shfl(mc1, src, 64);
        const float c2 = __shfl(mc2, src, 64);
        const float c3 = __shfl(mc3, src, 64);
        const float c4 = __shfl(mc4, src, 64);
        const float dx = __shfl(mdx, src, 64);
        const float dy = __shfl(mdy, src, 64);
        const float dz = __shfl(mdz, src, 64);

        const float qi = qarr[iq];                // coalesced direct
        const float ux = sU[cur][tid*3+0];
        const float uy = sU[cur][tid*3+1];
        const float uz = sU[cur][tid*3+2];
        const float xx = sQ[cur][tid*9+0];
        const float yy = sQ[cur][tid*9+4];
        const float zz = sQ[cur][tid*9+8];
        const float xy = 0.5f*(sQ[cur][tid*9+1] + sQ[cur][tid*9+3]);
        const float xz = 0.5f*(sQ[cur][tid*9+2] + sQ[cur][tid*9+6]);
        const float yz = 0.5f*(sQ[cur][tid*9+5] + sQ[cur][tid*9+7]);
        const float tqi = xx + yy + zz;

        const float ud  = ux*dx + uy*dy + uz*dz;
        const float Pdx = xx*dx + xy*dy + xz*dz;
        const float Pdy = xy*dx + yy*dy + yz*dz;
        const float Pdz = xz*dx + yz*dy + zz*dz;
        const float Pdd = Pdx*dx + Pdy*dy + Pdz*dz;

        const float t0 = c0 * qi;
        e0  += t0;
        eph += t0 - c1*ud + 0.5f*(c2*Pdd + c1*tqi);

        const float cH = 0.5f*(c2*(ud - tqi) - c3*Pdd);
        const float cF = cH + 0.5f*c2*ud - c1*qi;
        const float c1h = 0.5f * c1;
        Fx += cF*dx + c1*ux - c2*Pdx;
        Fy += cF*dy + c1*uy - c2*Pdy;
        Fz += cF*dz + c1*uz - c2*Pdz;
        Hx += cH*dx + c1h*ux - c2*Pdx;
        Hy += cH*dy + c1h*uy - c2*Pdy;
        Hz += cH*dz + c1h*uz - c2*Pdz;

        const float Rdx = jxx*dx + jxy*dy + jxz*dz;
        const float Rdy = jxy*dx + jyy*dy + jyz*dz;
        const float Rdz = jxz*dx + jyz*dy + jzz*dz;
        const float Rdd = Rdx*dx + Rdy*dy + Rdz*dz;
        const float dPR = Pdx*Rdx + Pdy*Rdy + Pdz*Rdz;
        const float frob = xx*jxx + yy*jyy + zz*jzz + 2.0f*(xy*jxy + xz*jxz + yz*jyz);
        pQQ += c4*(Pdd*Rdd)
             + c3*(jtq*Pdd + tqi*Rdd + 4.0f*dPR)
             + c2*(tqi*jtq + 2.0f*frob);

        // one barrier/iter: all reads of buf[cur] done before iter k+1
        // overwrites it; all writes to buf[nxt] done before iter k+1 reads it.
        __syncthreads();
    }

    // ---- reduction: segs within wave (offsets 8,16,32), then cross-wave LDS ----
    float acc[9] = {e0, eph, Fx, Fy, Fz, Hx, Hy, Hz, pQQ};
    #pragma unroll
    for (int off = 8; off < 64; off <<= 1) {
        #pragma unroll
        for (int c = 0; c < 9; ++c) acc[c] += __shfl_xor(acc[c], off, 64);
    }
    __shared__ float red[8][8][9];
    if ((lane & 56) == 0) {
        #pragma unroll
        for (int c = 0; c < 9; ++c) red[wv][lane][c] = acc[c];
    }
    __syncthreads();
    if (tid < 8) {
        float v[9];
        #pragma unroll
        for (int c = 0; c < 9; ++c) {
            float s = 0.f;
            #pragma unroll
            for (int w = 0; w < 8; ++w) s += red[w][tid][c];
            v[c] = s;
        }
        const float te0 = v[0], teph = v[1];
        const float tFx = v[2], tFy = v[3], tFz = v[4];
        const float tHx = v[5], tHy = v[6], tHz = v[7];
        const float tQQ = v[8] * 0.125f;
        const int myjq = j * NQC + tid;
        const float qj  = qarr[myjq];
        const float ujx = uarr[myjq*3+0], ujy = uarr[myjq*3+1], ujz = uarr[myjq*3+2];
        const float kapv = kaparr[myjq];
        const float alpv = alparr[myjq];

        float pot = qj * (teph - 0.5f*te0)
                  - (ujx*tHx + ujy*tHy + ujz*tHz)
                  + tQQ
                  - 0.5f * kapv * teph * teph
                  - 0.5f * alpv * (tFx*tFx + tFy*tFy + tFz*tFz);

        out[1 + myjq] = -kapv * teph;
        out[1 + NA*NQC + myjq*3 + 0] = alpv * tFx;
        out[1 + NA*NQC + myjq*3 + 1] = alpv * tFy;
        out[1 + NA*NQC + myjq*3 + 2] = alpv * tFz;

        // per-block pot partial -> plain store (no same-address atomic tail)
        #pragma unroll
        for (int off = 4; off; off >>= 1) pot += __shfl_xor(pot, off, 8);
        if (tid == 0) potpart[j] = pot;
    }
}

// ---------------- pot reduction (deterministic, 1 block) ----------------
__global__ void pot_kernel(const float* __restrict__ potpart, float* __restrict__ out) {
    const int tid = threadIdx.x;    // 512 threads, 1 block
    float p = potpart[tid];
    #pragma unroll
    for (int off = 32; off; off >>= 1) p += __shfl_xor(p, off, 64);
    __shared__ float l[8];
    if ((tid & 63) == 0) l[tid >> 6] = p;
    __syncthreads();
    if (tid == 0) {
        float s = 0.f;
        #pragma unroll
        for (int w = 0; w < 8; ++w) s += l[w];
        out[0] = s;
    }
}

extern "C" void kernel_launch(void* const* d_in, const int* in_sizes, int n_in,
                              void* d_out, int out_size, void* d_ws, size_t ws_size,
                              hipStream_t stream) {
    const float* q    = (const float*)d_in[0];
    const float* r    = (const float*)d_in[1];
    const float* u    = (const float*)d_in[4];
    const float* quad = (const float*)d_in[5];
    const float* kap  = (const float*)d_in[6];
    const float* alp  = (const float*)d_in[7];
    float* out = (float*)d_out;
    float* potpart = (float*)d_ws;   // 512 floats
    (void)ws_size; (void)in_sizes; (void)n_in; (void)out_size;

    main_kernel<<<NA, 512, 0, stream>>>(q, r, u, quad, kap, alp, out, potpart);
    pot_kernel<<<1, 512, 0, stream>>>(potpart, out);
}

// Round 13
// 17.506 us; speedup vs baseline: 1.2024x; 1.2024x over previous
//
#include <hip/hip_runtime.h>
#include <math.h>

#define NA 512
#define NQC 8

#define NCf ((float)(90.4756 / 6.28318530717958647692))
#define A_ERF 0.70710678118654752f      // 1/sqrt(2)
#define G_COEF 0.79788456080286536f     // sqrt(2/pi)

// ---------------- main kernel ----------------
// grid = 512 blocks (receiver j), block = 512 threads = 8 waves.
// Wave-level coefficient sharing via a wave-private LDS table: the coef pass
// stores each lane's pair record (c0..c4,dx,dy,dz) as 2xfloat4; the k-loop
// fetches the needed pair with 2 ds_read_b128 broadcasts (replaces 8
// ds_bpermute + addr setup). No barrier: same wave writes and reads.
// F/H accumulators split as H and G=F-H (2-FMA increment), F=H+G post-loop.
// Moment loads stay contiguous: iq = k*512 + tid.
__global__ __launch_bounds__(512)
void main_kernel(const float* __restrict__ qarr,
                 const float* __restrict__ rarr,
                 const float* __restrict__ uarr,
                 const float* __restrict__ quadarr,
                 const float* __restrict__ kaparr,
                 const float* __restrict__ alparr,
                 float* __restrict__ out,
                 float* __restrict__ potpart) {
    const int j    = blockIdx.x;
    const int tid  = threadIdx.x;
    const int qch  = tid & 7;
    const int lane = tid & 63;
    const int wv   = tid >> 6;     // 8 waves

    __shared__ float sCo[8][64][8];   // 16 KB wave-private coefficient tables

    const float rjx = rarr[j*3+0], rjy = rarr[j*3+1], rjz = rarr[j*3+2];

    const int jq = j * NQC + qch;
    const float* Qj = quadarr + (size_t)jq * 9;
    const float jxx = Qj[0], jyy = Qj[4], jzz = Qj[8];
    const float jxy = 0.5f*(Qj[1]+Qj[3]);
    const float jxz = 0.5f*(Qj[2]+Qj[6]);
    const float jyz = 0.5f*(Qj[5]+Qj[7]);
    const float jtq = jxx + jyy + jzz;

    // ---- coefficient pass: one pair per lane (covers all 8 k-iters) ----
    {
        const int myi = ((lane >> 3) << 6) + (wv << 3) + (lane & 7);
        const float mdx = rjx - rarr[myi*3+0];
        const float mdy = rjy - rarr[myi*3+1];
        const float mdz = rjz - rarr[myi*3+2];
        float r2 = mdx*mdx + mdy*mdy + mdz*mdz;
        const bool diag = (myi == j);
        if (diag) r2 = 1.0f;
        const float ir  = rsqrtf(r2);
        const float rr  = r2 * ir;
        // branch-free erf(rr/sqrt(2)) — A&S 7.1.26, exp shared with G
        const float x   = A_ERF * rr;
        const float E2  = __expf(-0.5f * r2);  // == exp(-x*x)
        const float G   = G_COEF * E2;
        const float t   = __builtin_amdgcn_rcpf(fmaf(0.3275911f, x, 1.0f));
        const float pol = t*(0.254829592f + t*(-0.284496736f + t*(1.421413741f
                         + t*(-1.453152027f + t*1.061405429f))));
        const float E   = fmaf(-pol, E2, 1.0f);
        const float ir2 = ir * ir;
        const float ir4 = ir2 * ir2;
        const float g   = E * ir;
        const float GmG = G - g;
        const float nco = diag ? 0.0f : NCf;
        float4* slot = (float4*)&sCo[wv][lane][0];
        slot[0] = make_float4(nco * g,
                              nco * ir2 * GmG,
                              nco * ir2 * (-3.0f*ir2*GmG - G),
                              nco * ir2 * (15.0f*ir4*GmG + 5.0f*G*ir2 + G));
        slot[1] = make_float4(nco * ir2 * (-105.0f*ir4*ir2*GmG - 35.0f*G*ir4
                                           - 7.0f*G*ir2 - G),
                              mdx, mdy, mdz);
    }
    // no __syncthreads: table is wave-private (writer wave == reader wave)

    float e0 = 0.f, eph = 0.f;
    float Gx = 0.f, Gy = 0.f, Gz = 0.f;   // G = F - H
    float Hx = 0.f, Hy = 0.f, Hz = 0.f;
    float pQQ = 0.f;

    #pragma unroll 4
    for (int k = 0; k < 8; ++k) {
        const int iq = k * 512 + tid;             // == i*NQC + qch (contiguous)
        const int p  = (k << 3) + (lane >> 3);    // pair slot in wave table

        const float4 ca = *(const float4*)&sCo[wv][p][0];
        const float4 cb = *(const float4*)&sCo[wv][p][4];
        const float c0 = ca.x, c1 = ca.y, c2 = ca.z, c3 = ca.w;
        const float c4 = cb.x, dx = cb.y, dy = cb.z, dz = cb.w;

        const float qi = qarr[iq];
        const float ux = uarr[iq*3+0], uy = uarr[iq*3+1], uz = uarr[iq*3+2];
        const float* Qi = quadarr + (size_t)iq * 9;
        const float xx = Qi[0], yy = Qi[4], zz = Qi[8];
        const float xy = 0.5f*(Qi[1]+Qi[3]);
        const float xz = 0.5f*(Qi[2]+Qi[6]);
        const float yz = 0.5f*(Qi[5]+Qi[7]);
        const float tqi = xx + yy + zz;

        const float ud  = ux*dx + uy*dy + uz*dz;
        const float Pdx = xx*dx + xy*dy + xz*dz;
        const float Pdy = xy*dx + yy*dy + yz*dz;
        const float Pdz = xz*dx + yz*dy + zz*dz;
        const float Pdd = Pdx*dx + Pdy*dy + Pdz*dz;

        const float t0 = c0 * qi;
        e0  += t0;
        eph += t0 - c1*ud + 0.5f*(c2*Pdd + c1*tqi);

        const float c1h = 0.5f * c1;
        const float cH = 0.5f*(c2*(ud - tqi) - c3*Pdd);
        const float gf = 0.5f*c2*ud - c1*qi;      // cF - cH
        // H: 3 FMA/comp; G: 2 FMA/comp (F recovered as H+G after the loop)
        Hx += cH*dx + c1h*ux - c2*Pdx;
        Hy += cH*dy + c1h*uy - c2*Pdy;
        Hz += cH*dz + c1h*uz - c2*Pdz;
        Gx += gf*dx + c1h*ux;
        Gy += gf*dy + c1h*uy;
        Gz += gf*dz + c1h*uz;

        const float Rdx = jxx*dx + jxy*dy + jxz*dz;
        const float Rdy = jxy*dx + jyy*dy + jyz*dz;
        const float Rdz = jxz*dx + jyz*dy + jzz*dz;
        const float Rdd = Rdx*dx + Rdy*dy + Rdz*dz;
        const float dPR = Pdx*Rdx + Pdy*Rdy + Pdz*Rdz;
        const float frob = xx*jxx + yy*jyy + zz*jzz + 2.0f*(xy*jxy + xz*jxz + yz*jyz);
        pQQ += c4*(Pdd*Rdd)
             + c3*(jtq*Pdd + tqi*Rdd + 4.0f*dPR)
             + c2*(tqi*jtq + 2.0f*frob);
    }

    // recover F = H + G
    const float Fx = Hx + Gx, Fy = Hy + Gy, Fz = Hz + Gz;

    // ---- reduction: segs within wave (offsets 8,16,32), then cross-wave LDS ----
    float acc[9] = {e0, eph, Fx, Fy, Fz, Hx, Hy, Hz, pQQ};
    #pragma unroll
    for (int off = 8; off < 64; off <<= 1) {
        #pragma unroll
        for (int c = 0; c < 9; ++c) acc[c] += __shfl_xor(acc[c], off, 64);
    }
    __shared__ float red[8][8][9];
    if ((lane & 56) == 0) {
        #pragma unroll
        for (int c = 0; c < 9; ++c) red[wv][lane][c] = acc[c];
    }
    __syncthreads();
    if (tid < 8) {
        float v[9];
        #pragma unroll
        for (int c = 0; c < 9; ++c) {
            float s = 0.f;
            #pragma unroll
            for (int w = 0; w < 8; ++w) s += red[w][tid][c];
            v[c] = s;
        }
        const float te0 = v[0], teph = v[1];
        const float tFx = v[2], tFy = v[3], tFz = v[4];
        const float tHx = v[5], tHy = v[6], tHz = v[7];
        const float tQQ = v[8] * 0.125f;
        const int myjq = j * NQC + tid;
        const float qj  = qarr[myjq];
        const float ujx = uarr[myjq*3+0], ujy = uarr[myjq*3+1], ujz = uarr[myjq*3+2];
        const float kapv = kaparr[myjq];
        const float alpv = alparr[myjq];

        float pot = qj * (teph - 0.5f*te0)
                  - (ujx*tHx + ujy*tHy + ujz*tHz)
                  + tQQ
                  - 0.5f * kapv * teph * teph
                  - 0.5f * alpv * (tFx*tFx + tFy*tFy + tFz*tFz);

        out[1 + myjq] = -kapv * teph;
        out[1 + NA*NQC + myjq*3 + 0] = alpv * tFx;
        out[1 + NA*NQC + myjq*3 + 1] = alpv * tFy;
        out[1 + NA*NQC + myjq*3 + 2] = alpv * tFz;

        // per-block pot partial -> plain store (no same-address atomic tail)
        #pragma unroll
        for (int off = 4; off; off >>= 1) pot += __shfl_xor(pot, off, 8);
        if (tid == 0) potpart[j] = pot;
    }
}

// ---------------- pot reduction (deterministic, 1 wave) ----------------
__global__ void pot_kernel(const float* __restrict__ potpart, float* __restrict__ out) {
    const int t = threadIdx.x;    // 64 threads
    float s = 0.f;
    #pragma unroll
    for (int m = 0; m < 8; ++m) s += potpart[t + m*64];
    #pragma unroll
    for (int off = 32; off; off >>= 1) s += __shfl_xor(s, off, 64);
    if (t == 0) out[0] = s;
}

extern "C" void kernel_launch(void* const* d_in, const int* in_sizes, int n_in,
                              void* d_out, int out_size, void* d_ws, size_t ws_size,
                              hipStream_t stream) {
    const float* q    = (const float*)d_in[0];
    const float* r    = (const float*)d_in[1];
    const float* u    = (const float*)d_in[4];
    const float* quad = (const float*)d_in[5];
    const float* kap  = (const float*)d_in[6];
    const float* alp  = (const float*)d_in[7];
    float* out = (float*)d_out;
    float* potpart = (float*)d_ws;   // 512 floats
    (void)ws_size; (void)in_sizes; (void)n_in; (void)out_size;

    main_kernel<<<NA, 512, 0, stream>>>(q, r, u, quad, kap, alp, out, potpart);
    pot_kernel<<<1, 64, 0, stream>>>(potpart, out);
}